// Round 9
// baseline (235.403 us; speedup 1.0000x reference)
//
#include <hip/hip_runtime.h>
#include <hip/hip_bf16.h>

#define NUM_B 8
#define SEQ 1024
#define DIM 768
#define NH 12
#define DH 64

typedef __attribute__((ext_vector_type(8))) short bf16x8;
typedef __attribute__((ext_vector_type(4))) short bf16x4;
typedef __attribute__((ext_vector_type(4))) float floatx4;
typedef __attribute__((ext_vector_type(4))) unsigned short ushortx4;
typedef __attribute__((ext_vector_type(8))) unsigned short ushortx8;

__device__ __forceinline__ unsigned short f2bf(float f) {
  unsigned u = __float_as_uint(f);
  u += 0x7FFFu + ((u >> 16) & 1u);   // round-to-nearest-even
  return (unsigned short)(u >> 16);
}

// K=16 bf16 MFMA: A/B = 4 bf16 (2 VGPRs). gfx950 has v_mfma_f32_16x16x16_bf16.
__device__ __forceinline__ floatx4 mfma16(bf16x4 a, bf16x4 b, floatx4 c) {
#if __has_builtin(__builtin_amdgcn_mfma_f32_16x16x16bf16_1k)
  return __builtin_amdgcn_mfma_f32_16x16x16bf16_1k(a, b, c, 0, 0, 0);
#else
  asm("v_mfma_f32_16x16x16_bf16 %0, %1, %2, %3" : "=v"(c) : "v"(a), "v"(b), "v"(c));
  return c;
#endif
}

// async global->LDS, 16B per lane; LDS dest = wave-uniform base + lane*16
#define GLOAD16(g, l) __builtin_amdgcn_global_load_lds( \
    (const __attribute__((address_space(1))) unsigned int*)(g), \
    (__attribute__((address_space(3))) unsigned int*)(l), 16, 0, 0)

// ---------------- one-shot fp32 -> bf16 conversion (x, Wk, Wo) -------------
__global__ __launch_bounds__(256) void convert_kernel(
    const float* __restrict__ x, const float* __restrict__ Wk,
    const float* __restrict__ Wo, unsigned short* __restrict__ xb,
    unsigned short* __restrict__ Wkb, unsigned short* __restrict__ Wob)
{
  const int NX4 = (8192 * 768) / 4;
  const int NW4 = (768 * 768) / 4;
  int i = blockIdx.x * 256 + threadIdx.x;
  const float* s; unsigned short* d; int off;
  if (i < NX4)            { s = x;  d = xb;  off = i; }
  else if (i < NX4 + NW4) { s = Wk; d = Wkb; off = i - NX4; }
  else                    { s = Wo; d = Wob; off = i - NX4 - NW4; }
  float4 v = ((const float4*)s)[off];
  ushortx4 h;
  h.x = f2bf(v.x); h.y = f2bf(v.y); h.z = f2bf(v.z); h.w = f2bf(v.w);
  ((ushortx4*)d)[off] = h;
}

// ---------------- K projection + fused transpose ---------------------------
// 64(M) x 128(N), BK=64, dbuf LINEAR global_load_lds (m97-style), 3 blk/CU.
__global__ __launch_bounds__(256) void proj_k_kernel(
    const unsigned short* __restrict__ xb, const unsigned short* __restrict__ Wkb,
    const float* __restrict__ bk, unsigned short* __restrict__ Kbh,
    unsigned short* __restrict__ KbhT)
{
  __shared__ __align__(16) unsigned short smem[24576];   // 48 KB (2 x 24 KB)
  const int tid = threadIdx.x;
  const int lane = tid & 63;
  const int w = tid >> 6;
  const int wr = w >> 1, wc = w & 1;
  const int quad = lane >> 4, r16 = lane & 15;
  const int m0 = blockIdx.x * 64, n0 = blockIdx.y * 128;
  const int wbase = (tid & ~63);

  floatx4 acc[2][4] = {};

  auto stage = [&](int kt, int buf) {
    unsigned short* As = smem + buf * 12288;
    unsigned short* Bs = As + 4096;
#pragma unroll
    for (int i = 0; i < 2; ++i) {
      int c = tid + i * 256;
      int row = c >> 3, g = c & 7;
      GLOAD16(xb + (size_t)(m0 + row) * DIM + kt + g * 8,
              As + (size_t)(wbase + i * 256) * 8);
    }
#pragma unroll
    for (int i = 0; i < 4; ++i) {
      int c = tid + i * 256;
      int row = c >> 3, g = c & 7;
      GLOAD16(Wkb + (size_t)(n0 + row) * DIM + kt + g * 8,
              Bs + (size_t)(wbase + i * 256) * 8);
    }
  };

  stage(0, 0);
  int buf = 0;
  for (int it = 0; it < 12; ++it) {
    __syncthreads();
    if (it + 1 < 12) stage((it + 1) * 64, buf ^ 1);
    const unsigned short* As = smem + buf * 12288;
    const unsigned short* Bs = As + 4096;
    bf16x8 af[2][2], bfm[4][2];
#pragma unroll
    for (int mi = 0; mi < 2; ++mi)
#pragma unroll
      for (int kc = 0; kc < 2; ++kc)
        af[mi][kc] = *(const bf16x8*)&As[(wr * 32 + mi * 16 + r16) * 64 + kc * 32 + quad * 8];
#pragma unroll
    for (int ni = 0; ni < 4; ++ni)
#pragma unroll
      for (int kc = 0; kc < 2; ++kc)
        bfm[ni][kc] = *(const bf16x8*)&Bs[(wc * 64 + ni * 16 + r16) * 64 + kc * 32 + quad * 8];
#pragma unroll
    for (int mi = 0; mi < 2; ++mi)
#pragma unroll
      for (int ni = 0; ni < 4; ++ni) {
        acc[mi][ni] = __builtin_amdgcn_mfma_f32_16x16x32_bf16(af[mi][0], bfm[ni][0], acc[mi][ni], 0, 0, 0);
        acc[mi][ni] = __builtin_amdgcn_mfma_f32_16x16x32_bf16(af[mi][1], bfm[ni][1], acc[mi][ni], 0, 0, 0);
      }
    buf ^= 1;
  }

  __syncthreads();                       // reuse smem as Ct [128 n][72]
  unsigned short* Ct = smem;
  const int bb = m0 >> 10, l0 = m0 & 1023;
#pragma unroll
  for (int mi = 0; mi < 2; ++mi)
#pragma unroll
    for (int ni = 0; ni < 4; ++ni) {
      int col = n0 + wc * 64 + ni * 16 + r16;   // j = h*64+dh
      float bias = bk[col];
      int hh = col >> 6, dd = col & 63;
      ushortx4 pk;
#pragma unroll
      for (int r = 0; r < 4; ++r) {
        int mrow = wr * 32 + mi * 16 + quad * 4 + r;
        unsigned short us = f2bf(acc[mi][ni][r] + bias);
        Kbh[((size_t)(bb * NH + hh) * SEQ + l0 + mrow) * DH + dd] = us;
        pk[r] = us;
      }
      *(ushortx4*)&Ct[(wc * 64 + ni * 16 + r16) * 72 + wr * 32 + mi * 16 + quad * 4] = pk;
    }
  __syncthreads();
#pragma unroll
  for (int i = 0; i < 4; ++i) {
    int c = tid + i * 256;
    int row = c >> 3, ch = c & 7;
    ushortx8 v = *(const ushortx8*)&Ct[row * 72 + ch * 8];
    int j = n0 + row;
    int hh = j >> 6, dd = j & 63;
    *(ushortx8*)&KbhT[((size_t)(bb * NH + hh) * DH + dd) * SEQ + l0 + ch * 8] = v;
  }
}

// ---------------- fused attention: register-P --------------------------------
// grid (qt=8, bh=96). 128 q/block, 4 waves x 32 q. St = K*Q^T (C-layout gives
// lane keys quad*4+r == A-layout of 16x16x16 MFMA) -> exp+pack in REGISTERS,
// PV via mfma_f32_16x16x16_bf16. No P LDS buffer; LDS = 32.5 KB -> 4 blk/CU.
__global__ __launch_bounds__(256) void attn_kernel(
    const unsigned short* __restrict__ Kbh, const unsigned short* __restrict__ KbhT,
    const int* __restrict__ mask, unsigned short* __restrict__ wV)
{
  __shared__ __align__(16) unsigned short smem[16640];   // 32 KB dbuf + 512 B rsum
  float* rsum = (float*)&smem[16384];

  const int tid = threadIdx.x;
  const int lane = tid & 63;
  const int w = tid >> 6;
  const int quad = lane >> 4, r16 = lane & 15;
  const int qt = blockIdx.x, bh = blockIdx.y;
  const int b = bh / NH, h = bh % NH;
  const unsigned short* Kb  = Kbh  + (size_t)bh * SEQ * DH;
  const unsigned short* KbT = KbhT + (size_t)bh * DH * SEQ;
  const int q0 = qt * 128;
  const int qw = w * 32;
  const int wbase = (tid & ~63);
  const float SCALE = 0.036084391824351615f;  // 1/sqrt(768)

  bf16x8 aq[2][2];
#pragma unroll
  for (int nt = 0; nt < 2; ++nt)
#pragma unroll
    for (int kc = 0; kc < 2; ++kc)
      aq[nt][kc] = *(const bf16x8*)(Kb + (size_t)(q0 + qw + nt * 16 + r16) * DH + kc * 32 + quad * 8);

  // mask folded into scale: masked row -> arg 0 -> p=1 (uniform softmax)
  float scm[2];
#pragma unroll
  for (int nt = 0; nt < 2; ++nt)
    scm[nt] = (mask[b * SEQ + q0 + qw + nt * 16 + r16] != 0) ? SCALE : 0.0f;

  floatx4 accO[2][4] = {};
  float psum[2] = {};

  auto stage = [&](int kt, int buf) {
    unsigned short* Ks  = smem + buf * 4096;
    unsigned short* KTs = smem + 8192 + buf * 4096;
#pragma unroll
    for (int i = 0; i < 2; ++i) {
      int c = tid + i * 256;
      GLOAD16(Kb + (size_t)kt * DH + (size_t)c * 8,
              Ks + (size_t)(wbase + i * 256) * 8);
    }
#pragma unroll
    for (int i = 0; i < 2; ++i) {
      int c = tid + i * 256;
      int row = c >> 3, g = c & 7;
      GLOAD16(KbT + (size_t)row * SEQ + kt + g * 8,
              KTs + (size_t)(wbase + i * 256) * 8);
    }
  };

  stage(0, 0);
  int buf = 0;
  for (int it = 0; it < SEQ / 64; ++it) {
    __syncthreads();
    if (it + 1 < SEQ / 64) stage((it + 1) * 64, buf ^ 1);
    const unsigned short* Ks  = smem + buf * 4096;
    const unsigned short* KTs = smem + 8192 + buf * 4096;

    // St[key][q] = K Q^T ; A = K-frag (m=key), B = aq (n=q)
    floatx4 St[4][2] = {};
#pragma unroll
    for (int kt = 0; kt < 4; ++kt) {
      int rb = (kt * 16 + r16) * 64;
      bf16x8 k0 = *(const bf16x8*)&Ks[rb + quad * 8];
      bf16x8 k1 = *(const bf16x8*)&Ks[rb + 32 + quad * 8];
#pragma unroll
      for (int nt = 0; nt < 2; ++nt) {
        St[kt][nt] = __builtin_amdgcn_mfma_f32_16x16x32_bf16(k0, aq[nt][0], St[kt][nt], 0, 0, 0);
        St[kt][nt] = __builtin_amdgcn_mfma_f32_16x16x32_bf16(k1, aq[nt][1], St[kt][nt], 0, 0, 0);
      }
    }

    // exp + pack IN REGISTERS: St lane layout (key=kt*16+quad*4+r, q=nt*16+r16)
    // == A-operand layout of mfma_16x16x16 (k=quad*4+j, m=r16). No LDS for P.
    bf16x4 pf[4][2];
#pragma unroll
    for (int nt = 0; nt < 2; ++nt) {
      float sc = scm[nt];
#pragma unroll
      for (int kt = 0; kt < 4; ++kt) {
        float p0 = __expf(St[kt][nt][0] * sc);
        float p1 = __expf(St[kt][nt][1] * sc);
        float p2 = __expf(St[kt][nt][2] * sc);
        float p3 = __expf(St[kt][nt][3] * sc);
        psum[nt] += (p0 + p1) + (p2 + p3);
        __hip_bfloat162 lo = __float22bfloat162_rn(make_float2(p0, p1));
        __hip_bfloat162 hi = __float22bfloat162_rn(make_float2(p2, p3));
        unsigned u0, u1;
        __builtin_memcpy(&u0, &lo, 4);
        __builtin_memcpy(&u1, &hi, 4);
        uint2 t = make_uint2(u0, u1);
        __builtin_memcpy(&pf[kt][nt], &t, 8);
      }
    }

    // O += P V : B-frag (k=key quad*4+j, n=dh r16) = b64 from KTs row dh
#pragma unroll
    for (int ni = 0; ni < 4; ++ni) {
      int rb = (ni * 16 + r16) * 64;
#pragma unroll
      for (int kt = 0; kt < 4; ++kt) {
        bf16x4 bv = *(const bf16x4*)&KTs[rb + kt * 16 + quad * 4];
#pragma unroll
        for (int mi = 0; mi < 2; ++mi)
          accO[mi][ni] = mfma16(pf[kt][mi], bv, accO[mi][ni]);
      }
    }
    buf ^= 1;
  }

  // psum at q=nt*16+r16 is quad-partial: reduce over quads, LDS hop to
  // re-align with the O epilogue's q = quad*4+r layout (same-wave in-order).
#pragma unroll
  for (int nt = 0; nt < 2; ++nt) {
    float s = psum[nt];
    s += __shfl_xor(s, 16);
    s += __shfl_xor(s, 32);
    psum[nt] = s;
  }
  if (quad == 0) {
#pragma unroll
    for (int nt = 0; nt < 2; ++nt)
      rsum[qw + nt * 16 + r16] = psum[nt];
  }
  float rinv[2][4];
#pragma unroll
  for (int mi = 0; mi < 2; ++mi)
#pragma unroll
    for (int r = 0; r < 4; ++r)
      rinv[mi][r] = 1.0f / rsum[qw + mi * 16 + quad * 4 + r];

#pragma unroll
  for (int mi = 0; mi < 2; ++mi)
#pragma unroll
    for (int ni = 0; ni < 4; ++ni)
#pragma unroll
      for (int r = 0; r < 4; ++r) {
        int l = q0 + qw + mi * 16 + quad * 4 + r;
        int col = h * DH + ni * 16 + r16;
        wV[(size_t)(b * SEQ + l) * DIM + col] = f2bf(accO[mi][ni][r] * rinv[mi][r]);
      }
}

// ---------------- output projection: out = wV @ Wo^T + bo (fp32) -----------
__global__ __launch_bounds__(256) void proj_o_kernel(
    const unsigned short* __restrict__ wVb, const unsigned short* __restrict__ Wob,
    const float* __restrict__ bo, float* __restrict__ out)
{
  __shared__ __align__(16) unsigned short smem[24576];   // 48 KB
  const int tid = threadIdx.x;
  const int lane = tid & 63;
  const int w = tid >> 6;
  const int wr = w >> 1, wc = w & 1;
  const int quad = lane >> 4, r16 = lane & 15;
  const int m0 = blockIdx.x * 64, n0 = blockIdx.y * 128;
  const int wbase = (tid & ~63);

  floatx4 acc[2][4] = {};

  auto stage = [&](int kt, int buf) {
    unsigned short* As = smem + buf * 12288;
    unsigned short* Bs = As + 4096;
#pragma unroll
    for (int i = 0; i < 2; ++i) {
      int c = tid + i * 256;
      int row = c >> 3, g = c & 7;
      GLOAD16(wVb + (size_t)(m0 + row) * DIM + kt + g * 8,
              As + (size_t)(wbase + i * 256) * 8);
    }
#pragma unroll
    for (int i = 0; i < 4; ++i) {
      int c = tid + i * 256;
      int row = c >> 3, g = c & 7;
      GLOAD16(Wob + (size_t)(n0 + row) * DIM + kt + g * 8,
              Bs + (size_t)(wbase + i * 256) * 8);
    }
  };

  stage(0, 0);
  int buf = 0;
  for (int it = 0; it < 12; ++it) {
    __syncthreads();
    if (it + 1 < 12) stage((it + 1) * 64, buf ^ 1);
    const unsigned short* As = smem + buf * 12288;
    const unsigned short* Bs = As + 4096;
    bf16x8 af[2][2], bfm[4][2];
#pragma unroll
    for (int mi = 0; mi < 2; ++mi)
#pragma unroll
      for (int kc = 0; kc < 2; ++kc)
        af[mi][kc] = *(const bf16x8*)&As[(wr * 32 + mi * 16 + r16) * 64 + kc * 32 + quad * 8];
#pragma unroll
    for (int ni = 0; ni < 4; ++ni)
#pragma unroll
      for (int kc = 0; kc < 2; ++kc)
        bfm[ni][kc] = *(const bf16x8*)&Bs[(wc * 64 + ni * 16 + r16) * 64 + kc * 32 + quad * 8];
#pragma unroll
    for (int mi = 0; mi < 2; ++mi)
#pragma unroll
      for (int ni = 0; ni < 4; ++ni) {
        acc[mi][ni] = __builtin_amdgcn_mfma_f32_16x16x32_bf16(af[mi][0], bfm[ni][0], acc[mi][ni], 0, 0, 0);
        acc[mi][ni] = __builtin_amdgcn_mfma_f32_16x16x32_bf16(af[mi][1], bfm[ni][1], acc[mi][ni], 0, 0, 0);
      }
    buf ^= 1;
  }

#pragma unroll
  for (int mi = 0; mi < 2; ++mi)
#pragma unroll
    for (int ni = 0; ni < 4; ++ni) {
      int col = n0 + wc * 64 + ni * 16 + r16;
      float bias = bo[col];
#pragma unroll
      for (int r = 0; r < 4; ++r) {
        int row = m0 + wr * 32 + mi * 16 + quad * 4 + r;
        out[(size_t)row * DIM + col] = acc[mi][ni][r] + bias;
      }
    }
}

extern "C" void kernel_launch(void* const* d_in, const int* in_sizes, int n_in,
                              void* d_out, int out_size, void* d_ws, size_t ws_size,
                              hipStream_t stream) {
  // inputs: x, attention_mask, Wq, bq, Wk, bk, Wv, bv, Wo, bo  (Q dead; V==K)
  const float* x  = (const float*)d_in[0];
  const int* mask = (const int*)d_in[1];
  const float* Wk = (const float*)d_in[4];
  const float* bk = (const float*)d_in[5];
  const float* Wo = (const float*)d_in[8];
  const float* bo = (const float*)d_in[9];
  float* out = (float*)d_out;

  unsigned short* p = (unsigned short*)d_ws;
  unsigned short* xb   = p;  p += (size_t)8192 * 768;
  unsigned short* Wkb  = p;  p += (size_t)768 * 768;
  unsigned short* Wob  = p;  p += (size_t)768 * 768;
  unsigned short* Kbh  = p;  p += (size_t)NUM_B * NH * SEQ * DH;
  unsigned short* KbhT = p;  p += (size_t)NUM_B * NH * SEQ * DH;
  unsigned short* wVb  = p;  // [8192][768]

  convert_kernel<<<7296, 256, 0, stream>>>(x, Wk, Wo, xb, Wkb, Wob);
  proj_k_kernel<<<dim3(128, 6), 256, 0, stream>>>(xb, Wkb, bk, Kbh, KbhT);
  attn_kernel<<<dim3(8, NUM_B * NH), 256, 0, stream>>>(Kbh, KbhT, mask, wVb);
  proj_o_kernel<<<dim3(128, 6), 256, 0, stream>>>(wVb, Wob, bo, out);
}

// Round 10
// 205.680 us; speedup vs baseline: 1.1445x; 1.1445x over previous
//
#include <hip/hip_runtime.h>
#include <hip/hip_bf16.h>

#define NUM_B 8
#define SEQ 1024
#define DIM 768
#define NH 12
#define DH 64

typedef __attribute__((ext_vector_type(8))) short bf16x8;
typedef __attribute__((ext_vector_type(4))) float floatx4;
typedef __attribute__((ext_vector_type(4))) unsigned short ushortx4;
typedef __attribute__((ext_vector_type(8))) unsigned short ushortx8;

__device__ __forceinline__ unsigned short f2bf(float f) {
  unsigned u = __float_as_uint(f);
  u += 0x7FFFu + ((u >> 16) & 1u);   // round-to-nearest-even
  return (unsigned short)(u >> 16);
}

__device__ __forceinline__ float fexp2(float x) {
#if __has_builtin(__builtin_amdgcn_exp2f)
  return __builtin_amdgcn_exp2f(x);     // bare v_exp_f32
#else
  return __expf(x * 0.6931471805599453f);
#endif
}

// async global->LDS, 16B per lane; LDS dest = wave-uniform base + lane*16
#define GLOAD16(g, l) __builtin_amdgcn_global_load_lds( \
    (const __attribute__((address_space(1))) unsigned int*)(g), \
    (__attribute__((address_space(3))) unsigned int*)(l), 16, 0, 0)

// ---------------- one-shot fp32 -> bf16 conversion (x, Wk, Wo) -------------
__global__ __launch_bounds__(256) void convert_kernel(
    const float* __restrict__ x, const float* __restrict__ Wk,
    const float* __restrict__ Wo, unsigned short* __restrict__ xb,
    unsigned short* __restrict__ Wkb, unsigned short* __restrict__ Wob)
{
  const int NX4 = (8192 * 768) / 4;
  const int NW4 = (768 * 768) / 4;
  int i = blockIdx.x * 256 + threadIdx.x;
  const float* s; unsigned short* d; int off;
  if (i < NX4)            { s = x;  d = xb;  off = i; }
  else if (i < NX4 + NW4) { s = Wk; d = Wkb; off = i - NX4; }
  else                    { s = Wo; d = Wob; off = i - NX4 - NW4; }
  float4 v = ((const float4*)s)[off];
  ushortx4 h;
  h.x = f2bf(v.x); h.y = f2bf(v.y); h.z = f2bf(v.z); h.w = f2bf(v.w);
  ((ushortx4*)d)[off] = h;
}

// ---------------- K projection + fused transpose ---------------------------
// 64(M) x 128(N), BK=64, dbuf linear global_load_lds, grid 768 (3/CU).
__global__ __launch_bounds__(256) void proj_k_kernel(
    const unsigned short* __restrict__ xb, const unsigned short* __restrict__ Wkb,
    const float* __restrict__ bk, unsigned short* __restrict__ Kbh,
    unsigned short* __restrict__ KbhT)
{
  __shared__ __align__(16) unsigned short smem[24576];   // 48 KB (2 x 24 KB)
  const int tid = threadIdx.x;
  const int lane = tid & 63;
  const int w = tid >> 6;
  const int wr = w >> 1, wc = w & 1;
  const int quad = lane >> 4, r16 = lane & 15;
  const int m0 = blockIdx.x * 64, n0 = blockIdx.y * 128;
  const int wbase = (tid & ~63);

  floatx4 acc[2][4] = {};

  auto stage = [&](int kt, int buf) {
    unsigned short* As = smem + buf * 12288;
    unsigned short* Bs = As + 4096;
#pragma unroll
    for (int i = 0; i < 2; ++i) {
      int c = tid + i * 256;
      int row = c >> 3, g = c & 7;
      GLOAD16(xb + (size_t)(m0 + row) * DIM + kt + g * 8,
              As + (size_t)(wbase + i * 256) * 8);
    }
#pragma unroll
    for (int i = 0; i < 4; ++i) {
      int c = tid + i * 256;
      int row = c >> 3, g = c & 7;
      GLOAD16(Wkb + (size_t)(n0 + row) * DIM + kt + g * 8,
              Bs + (size_t)(wbase + i * 256) * 8);
    }
  };

  stage(0, 0);
  int buf = 0;
  for (int it = 0; it < 12; ++it) {
    __syncthreads();
    if (it + 1 < 12) stage((it + 1) * 64, buf ^ 1);
    const unsigned short* As = smem + buf * 12288;
    const unsigned short* Bs = As + 4096;
    bf16x8 af[2][2], bfm[4][2];
#pragma unroll
    for (int mi = 0; mi < 2; ++mi)
#pragma unroll
      for (int kc = 0; kc < 2; ++kc)
        af[mi][kc] = *(const bf16x8*)&As[(wr * 32 + mi * 16 + r16) * 64 + kc * 32 + quad * 8];
#pragma unroll
    for (int ni = 0; ni < 4; ++ni)
#pragma unroll
      for (int kc = 0; kc < 2; ++kc)
        bfm[ni][kc] = *(const bf16x8*)&Bs[(wc * 64 + ni * 16 + r16) * 64 + kc * 32 + quad * 8];
#pragma unroll
    for (int mi = 0; mi < 2; ++mi)
#pragma unroll
      for (int ni = 0; ni < 4; ++ni) {
        acc[mi][ni] = __builtin_amdgcn_mfma_f32_16x16x32_bf16(af[mi][0], bfm[ni][0], acc[mi][ni], 0, 0, 0);
        acc[mi][ni] = __builtin_amdgcn_mfma_f32_16x16x32_bf16(af[mi][1], bfm[ni][1], acc[mi][ni], 0, 0, 0);
      }
    buf ^= 1;
  }

  __syncthreads();                       // reuse smem as Ct [128 n][72]
  unsigned short* Ct = smem;
  const int bb = m0 >> 10, l0 = m0 & 1023;
#pragma unroll
  for (int mi = 0; mi < 2; ++mi)
#pragma unroll
    for (int ni = 0; ni < 4; ++ni) {
      int col = n0 + wc * 64 + ni * 16 + r16;   // j = h*64+dh
      float bias = bk[col];
      int hh = col >> 6, dd = col & 63;
      ushortx4 pk;
#pragma unroll
      for (int r = 0; r < 4; ++r) {
        int mrow = wr * 32 + mi * 16 + quad * 4 + r;
        unsigned short us = f2bf(acc[mi][ni][r] + bias);
        Kbh[((size_t)(bb * NH + hh) * SEQ + l0 + mrow) * DH + dd] = us;
        pk[r] = us;
      }
      *(ushortx4*)&Ct[(wc * 64 + ni * 16 + r16) * 72 + wr * 32 + mi * 16 + quad * 4] = pk;
    }
  __syncthreads();
#pragma unroll
  for (int i = 0; i < 4; ++i) {
    int c = tid + i * 256;
    int row = c >> 3, ch = c & 7;
    ushortx8 v = *(const ushortx8*)&Ct[row * 72 + ch * 8];
    int j = n0 + row;
    int hh = j >> 6, dd = j & 63;
    *(ushortx8*)&KbhT[((size_t)(bb * NH + hh) * DH + dd) * SEQ + l0 + ch * 8] = v;
  }
}

// ---------------- fused attention: 256-q tile ------------------------------
// grid (qt=4, bh=96) = 384 blocks. 4 waves x 64 q. St = K*Q^T transposed-S;
// P via Ps LDS (stride 68, conflict-free b64 writes / b128 reads).
// Halved staged bytes vs 128-q tile: 4 blocks/bh re-stream K+KT, not 8.
__global__ __launch_bounds__(256) void attn_kernel(
    const unsigned short* __restrict__ Kbh, const unsigned short* __restrict__ KbhT,
    const int* __restrict__ mask, unsigned short* __restrict__ wV)
{
  __shared__ __align__(16) unsigned short smem[34304];  // 67 KB: dbuf 32K + Ps 34K + rsum 1K
  unsigned short* Ps = smem + 16384;      // [256][68]
  float* rsum = (float*)&smem[16384 + 17408];

  const int tid = threadIdx.x;
  const int lane = tid & 63;
  const int w = tid >> 6;
  const int quad = lane >> 4, r16 = lane & 15;
  const int qt = blockIdx.x, bh = blockIdx.y;
  const int b = bh / NH, h = bh % NH;
  const unsigned short* Kb  = Kbh  + (size_t)bh * SEQ * DH;
  const unsigned short* KbT = KbhT + (size_t)bh * DH * SEQ;
  const int q0 = qt * 256;
  const int qw = w * 64;
  const int wbase = (tid & ~63);
  const float SC2 = 0.05205809663084291f;  // (1/sqrt(768)) * log2(e)

  bf16x8 aq[4][2];
#pragma unroll
  for (int nt = 0; nt < 4; ++nt)
#pragma unroll
    for (int kc = 0; kc < 2; ++kc)
      aq[nt][kc] = *(const bf16x8*)(Kb + (size_t)(q0 + qw + nt * 16 + r16) * DH + kc * 32 + quad * 8);

  // mask folded into scale: masked row -> arg 0 -> 2^0 = 1 (uniform softmax)
  float scm[4];
#pragma unroll
  for (int nt = 0; nt < 4; ++nt)
    scm[nt] = (mask[b * SEQ + q0 + qw + nt * 16 + r16] != 0) ? SC2 : 0.0f;

  floatx4 accO[4][4] = {};
  float psum[4] = {};

  auto stage = [&](int kt, int buf) {
    unsigned short* Ks  = smem + buf * 4096;
    unsigned short* KTs = smem + 8192 + buf * 4096;
#pragma unroll
    for (int i = 0; i < 2; ++i) {
      int c = tid + i * 256;
      GLOAD16(Kb + (size_t)kt * DH + (size_t)c * 8,
              Ks + (size_t)(wbase + i * 256) * 8);
    }
#pragma unroll
    for (int i = 0; i < 2; ++i) {
      int c = tid + i * 256;
      int row = c >> 3, g = c & 7;
      GLOAD16(KbT + (size_t)row * SEQ + kt + g * 8,
              KTs + (size_t)(wbase + i * 256) * 8);
    }
  };

  stage(0, 0);
  int buf = 0;
  for (int it = 0; it < SEQ / 64; ++it) {
    __syncthreads();
    if (it + 1 < SEQ / 64) stage((it + 1) * 64, buf ^ 1);
    const unsigned short* Ks  = smem + buf * 4096;
    const unsigned short* KTs = smem + 8192 + buf * 4096;

    // St[key][q] = K Q^T ; per kt: 8 MFMA -> exp2 -> Ps (releases St regs)
#pragma unroll
    for (int kt = 0; kt < 4; ++kt) {
      int rb = (kt * 16 + r16) * 64;
      bf16x8 k0 = *(const bf16x8*)&Ks[rb + quad * 8];
      bf16x8 k1 = *(const bf16x8*)&Ks[rb + 32 + quad * 8];
      floatx4 St[4] = {};
#pragma unroll
      for (int nt = 0; nt < 4; ++nt) {
        St[nt] = __builtin_amdgcn_mfma_f32_16x16x32_bf16(k0, aq[nt][0], St[nt], 0, 0, 0);
        St[nt] = __builtin_amdgcn_mfma_f32_16x16x32_bf16(k1, aq[nt][1], St[nt], 0, 0, 0);
      }
#pragma unroll
      for (int nt = 0; nt < 4; ++nt) {
        float sc = scm[nt];
        float p0 = fexp2(St[nt][0] * sc);
        float p1 = fexp2(St[nt][1] * sc);
        float p2 = fexp2(St[nt][2] * sc);
        float p3 = fexp2(St[nt][3] * sc);
        psum[nt] += (p0 + p1) + (p2 + p3);
        __hip_bfloat162 lo = __float22bfloat162_rn(make_float2(p0, p1));
        __hip_bfloat162 hi = __float22bfloat162_rn(make_float2(p2, p3));
        unsigned u0, u1;
        __builtin_memcpy(&u0, &lo, 4);
        __builtin_memcpy(&u1, &hi, 4);
        *(uint2*)&Ps[(qw + nt * 16 + r16) * 68 + quad * 4 + kt * 16] = make_uint2(u0, u1);
      }
    }

    // O += P V (same-wave LDS RAW on Ps; V^T tile from KTs, b128 reads)
    bf16x8 ap[4][2];
#pragma unroll
    for (int mi = 0; mi < 4; ++mi)
#pragma unroll
      for (int kc = 0; kc < 2; ++kc)
        ap[mi][kc] = *(const bf16x8*)&Ps[(qw + mi * 16 + r16) * 68 + kc * 32 + quad * 8];
#pragma unroll
    for (int ni = 0; ni < 4; ++ni) {
      int rb = (ni * 16 + r16) * 64;
      bf16x8 v0 = *(const bf16x8*)&KTs[rb + quad * 8];
      bf16x8 v1 = *(const bf16x8*)&KTs[rb + 32 + quad * 8];
#pragma unroll
      for (int mi = 0; mi < 4; ++mi) {
        accO[mi][ni] = __builtin_amdgcn_mfma_f32_16x16x32_bf16(ap[mi][0], v0, accO[mi][ni], 0, 0, 0);
        accO[mi][ni] = __builtin_amdgcn_mfma_f32_16x16x32_bf16(ap[mi][1], v1, accO[mi][ni], 0, 0, 0);
      }
    }
    buf ^= 1;
  }

  // psum at q=nt*16+r16 is quad-partial: reduce over quads, LDS hop to
  // re-align with the O epilogue's q = quad*4+r layout (same-wave in-order).
#pragma unroll
  for (int nt = 0; nt < 4; ++nt) {
    float s = psum[nt];
    s += __shfl_xor(s, 16);
    s += __shfl_xor(s, 32);
    psum[nt] = s;
  }
  if (quad == 0) {
#pragma unroll
    for (int nt = 0; nt < 4; ++nt)
      rsum[qw + nt * 16 + r16] = psum[nt];
  }
  float rinv[4][4];
#pragma unroll
  for (int mi = 0; mi < 4; ++mi)
#pragma unroll
    for (int r = 0; r < 4; ++r)
      rinv[mi][r] = 1.0f / rsum[qw + mi * 16 + quad * 4 + r];

#pragma unroll
  for (int mi = 0; mi < 4; ++mi)
#pragma unroll
    for (int ni = 0; ni < 4; ++ni)
#pragma unroll
      for (int r = 0; r < 4; ++r) {
        int l = q0 + qw + mi * 16 + quad * 4 + r;
        int col = h * DH + ni * 16 + r16;
        wV[(size_t)(b * SEQ + l) * DIM + col] = f2bf(accO[mi][ni][r] * rinv[mi][r]);
      }
}

// ---------------- output projection: out = wV @ Wo^T + bo (fp32) -----------
__global__ __launch_bounds__(256) void proj_o_kernel(
    const unsigned short* __restrict__ wVb, const unsigned short* __restrict__ Wob,
    const float* __restrict__ bo, float* __restrict__ out)
{
  __shared__ __align__(16) unsigned short smem[24576];   // 48 KB
  const int tid = threadIdx.x;
  const int lane = tid & 63;
  const int w = tid >> 6;
  const int wr = w >> 1, wc = w & 1;
  const int quad = lane >> 4, r16 = lane & 15;
  const int m0 = blockIdx.x * 64, n0 = blockIdx.y * 128;
  const int wbase = (tid & ~63);

  floatx4 acc[2][4] = {};

  auto stage = [&](int kt, int buf) {
    unsigned short* As = smem + buf * 12288;
    unsigned short* Bs = As + 4096;
#pragma unroll
    for (int i = 0; i < 2; ++i) {
      int c = tid + i * 256;
      int row = c >> 3, g = c & 7;
      GLOAD16(wVb + (size_t)(m0 + row) * DIM + kt + g * 8,
              As + (size_t)(wbase + i * 256) * 8);
    }
#pragma unroll
    for (int i = 0; i < 4; ++i) {
      int c = tid + i * 256;
      int row = c >> 3, g = c & 7;
      GLOAD16(Wob + (size_t)(n0 + row) * DIM + kt + g * 8,
              Bs + (size_t)(wbase + i * 256) * 8);
    }
  };

  stage(0, 0);
  int buf = 0;
  for (int it = 0; it < 12; ++it) {
    __syncthreads();
    if (it + 1 < 12) stage((it + 1) * 64, buf ^ 1);
    const unsigned short* As = smem + buf * 12288;
    const unsigned short* Bs = As + 4096;
    bf16x8 af[2][2], bfm[4][2];
#pragma unroll
    for (int mi = 0; mi < 2; ++mi)
#pragma unroll
      for (int kc = 0; kc < 2; ++kc)
        af[mi][kc] = *(const bf16x8*)&As[(wr * 32 + mi * 16 + r16) * 64 + kc * 32 + quad * 8];
#pragma unroll
    for (int ni = 0; ni < 4; ++ni)
#pragma unroll
      for (int kc = 0; kc < 2; ++kc)
        bfm[ni][kc] = *(const bf16x8*)&Bs[(wc * 64 + ni * 16 + r16) * 64 + kc * 32 + quad * 8];
#pragma unroll
    for (int mi = 0; mi < 2; ++mi)
#pragma unroll
      for (int ni = 0; ni < 4; ++ni) {
        acc[mi][ni] = __builtin_amdgcn_mfma_f32_16x16x32_bf16(af[mi][0], bfm[ni][0], acc[mi][ni], 0, 0, 0);
        acc[mi][ni] = __builtin_amdgcn_mfma_f32_16x16x32_bf16(af[mi][1], bfm[ni][1], acc[mi][ni], 0, 0, 0);
      }
    buf ^= 1;
  }

#pragma unroll
  for (int mi = 0; mi < 2; ++mi)
#pragma unroll
    for (int ni = 0; ni < 4; ++ni) {
      int col = n0 + wc * 64 + ni * 16 + r16;
      float bias = bo[col];
#pragma unroll
      for (int r = 0; r < 4; ++r) {
        int row = m0 + wr * 32 + mi * 16 + quad * 4 + r;
        out[(size_t)row * DIM + col] = acc[mi][ni][r] + bias;
      }
    }
}

extern "C" void kernel_launch(void* const* d_in, const int* in_sizes, int n_in,
                              void* d_out, int out_size, void* d_ws, size_t ws_size,
                              hipStream_t stream) {
  // inputs: x, attention_mask, Wq, bq, Wk, bk, Wv, bv, Wo, bo  (Q dead; V==K)
  const float* x  = (const float*)d_in[0];
  const int* mask = (const int*)d_in[1];
  const float* Wk = (const float*)d_in[4];
  const float* bk = (const float*)d_in[5];
  const float* Wo = (const float*)d_in[8];
  const float* bo = (const float*)d_in[9];
  float* out = (float*)d_out;

  unsigned short* p = (unsigned short*)d_ws;
  unsigned short* xb   = p;  p += (size_t)8192 * 768;
  unsigned short* Wkb  = p;  p += (size_t)768 * 768;
  unsigned short* Wob  = p;  p += (size_t)768 * 768;
  unsigned short* Kbh  = p;  p += (size_t)NUM_B * NH * SEQ * DH;
  unsigned short* KbhT = p;  p += (size_t)NUM_B * NH * SEQ * DH;
  unsigned short* wVb  = p;  // [8192][768]

  convert_kernel<<<7296, 256, 0, stream>>>(x, Wk, Wo, xb, Wkb, Wob);
  proj_k_kernel<<<dim3(128, 6), 256, 0, stream>>>(xb, Wkb, bk, Kbh, KbhT);
  attn_kernel<<<dim3(4, NUM_B * NH), 256, 0, stream>>>(Kbh, KbhT, mask, wVb);
  proj_o_kernel<<<dim3(128, 6), 256, 0, stream>>>(wVb, Wob, bo, out);
}